// Round 1
// baseline (1639.581 us; speedup 1.0000x reference)
//
#include <hip/hip_runtime.h>
#include <math.h>

#define NEG_SLOPE 0.2f
#define FIN 128
#define H1 8
#define F1 64   // HEADS1*HID
#define F2 32   // OUT2

// ---------------- Layer-1 GEMM: h1 = x @ W1, fused e_src/e_dst ----------------
// one wave (64 lanes) per node; lane j computes h1[n,j]
__global__ void gemm1_kernel(const float* __restrict__ x, const float* __restrict__ W1,
                             const float* __restrict__ a_src, const float* __restrict__ a_dst,
                             float* __restrict__ h1, float* __restrict__ es, float* __restrict__ ed,
                             int N) {
    int n = blockIdx.x;
    if (n >= N) return;
    int j = threadIdx.x; // 0..63
    __shared__ float xs[FIN];
    xs[j]      = x[(size_t)n * FIN + j];
    xs[j + 64] = x[(size_t)n * FIN + 64 + j];
    __syncthreads();
    float acc = 0.f;
#pragma unroll
    for (int k = 0; k < FIN; ++k) acc = fmaf(xs[k], W1[k * F1 + j], acc);
    h1[(size_t)n * F1 + j] = acc;
    // e_src[n,h] = sum_c h[n,h,c]*a_src[h,c]; j = h*8+c
    float vs = acc * a_src[j];
    float vd = acc * a_dst[j];
#pragma unroll
    for (int off = 4; off >= 1; off >>= 1) {
        vs += __shfl_down(vs, off, 8);
        vd += __shfl_down(vd, off, 8);
    }
    if ((j & 7) == 0) {
        es[n * H1 + (j >> 3)] = vs;
        ed[n * H1 + (j >> 3)] = vd;
    }
}

// ---------------- zero-init (ws is re-poisoned 0xAA before every call) --------
__global__ void zero3_kernel(float* a, long long na, float* b, long long nb,
                             float* c, long long nc) {
    long long t = (long long)blockIdx.x * blockDim.x + threadIdx.x;
    long long stride = (long long)gridDim.x * blockDim.x;
    for (long long i = t; i < na; i += stride) a[i] = 0.f;
    for (long long i = t; i < nb; i += stride) b[i] = 0.f;
    for (long long i = t; i < nc; i += stride) c[i] = 0.f;
}

// ---------------- Layer-1 edge pass: unnormalized softmax-aggregate ----------
// thread t -> edge e = t>>6, channel j = t&63 (one wave per edge).
// w = exp(leaky(es[src,h]+ed[dst,h])); o1[dst,j] += w*h1[src,j]; den[dst,h] += w
__global__ void edge1_kernel(const int* __restrict__ ei, int E, int N,
                             const float* __restrict__ es, const float* __restrict__ ed,
                             const float* __restrict__ h1,
                             float* __restrict__ o1, float* __restrict__ den) {
    long long t = (long long)blockIdx.x * blockDim.x + threadIdx.x;
    long long total = (long long)(E + N) * F1;
    if (t >= total) return;
    int e = (int)(t >> 6);
    int j = (int)(t & 63);
    int h = j >> 3;
    int s, d;
    if (e < E) { s = ei[e]; d = ei[E + e]; } else { s = d = e - E; } // appended self-loops
    float v = es[s * H1 + h] + ed[d * H1 + h];
    v = v > 0.f ? v : v * NEG_SLOPE;
    float w = __expf(v);
    atomicAdd(&o1[(size_t)d * F1 + j], w * h1[(size_t)s * F1 + j]);
    if ((j & 7) == 0) atomicAdd(&den[d * H1 + h], w);
}

// ---------------- Layer-2 GEMM: a1 = elu(o1/den + b1); h2 = a1 @ W2 ----------
// 64 threads per block = 2 nodes, 32 lanes per node
__global__ void gemm2_kernel(const float* __restrict__ o1, const float* __restrict__ den1,
                             const float* __restrict__ b1, const float* __restrict__ W2,
                             const float* __restrict__ a_src2, const float* __restrict__ a_dst2,
                             float* __restrict__ h2, float* __restrict__ es2, float* __restrict__ ed2,
                             int N) {
    int half = threadIdx.x >> 5;
    int n = blockIdx.x * 2 + half;
    int j = threadIdx.x & 31;
    __shared__ float a1s[2][F1];
    if (n < N) {
#pragma unroll
        for (int r = 0; r < 2; ++r) {
            int k = r * 32 + j;
            float v = o1[(size_t)n * F1 + k] / den1[n * H1 + (k >> 3)] + b1[k];
            a1s[half][k] = v > 0.f ? v : expm1f(v); // ELU
        }
    }
    __syncthreads();
    if (n >= N) return;
    float acc = 0.f;
#pragma unroll
    for (int k = 0; k < F1; ++k) acc = fmaf(a1s[half][k], W2[k * F2 + j], acc);
    h2[(size_t)n * F2 + j] = acc;
    float vs = acc * a_src2[j];
    float vd = acc * a_dst2[j];
#pragma unroll
    for (int off = 16; off >= 1; off >>= 1) {
        vs += __shfl_down(vs, off, 32);
        vd += __shfl_down(vd, off, 32);
    }
    if (j == 0) { es2[n] = vs; ed2[n] = vd; }
}

// ---------------- Layer-2 edge pass (1 head, 32 channels) --------------------
__global__ void edge2_kernel(const int* __restrict__ ei, int E, int N,
                             const float* __restrict__ es, const float* __restrict__ ed,
                             const float* __restrict__ h2,
                             float* __restrict__ o2, float* __restrict__ den) {
    long long t = (long long)blockIdx.x * blockDim.x + threadIdx.x;
    long long total = (long long)(E + N) * F2;
    if (t >= total) return;
    int e = (int)(t >> 5);
    int j = (int)(t & 31);
    int s, d;
    if (e < E) { s = ei[e]; d = ei[E + e]; } else { s = d = e - E; }
    float v = es[s] + ed[d];
    v = v > 0.f ? v : v * NEG_SLOPE;
    float w = __expf(v);
    atomicAdd(&o2[(size_t)d * F2 + j], w * h2[(size_t)s * F2 + j]);
    if (j == 0) atomicAdd(&den[d], w);
}

// ---------------- Final: sum-pool (o2/den + b2) then dot Wr ------------------
__global__ void reduce_kernel(const float* __restrict__ o2, const float* __restrict__ den2,
                              const float* __restrict__ b2, const float* __restrict__ Wr,
                              float* __restrict__ pooled, int N) {
    long long t = (long long)blockIdx.x * blockDim.x + threadIdx.x;
    long long total = (long long)N * F2;
    long long stride = (long long)gridDim.x * blockDim.x;
    float part = 0.f;
    for (long long i = t; i < total; i += stride) {
        int j = (int)(i & 31);
        int n = (int)(i >> 5);
        part += (o2[i] / den2[n] + b2[j]) * Wr[j];
    }
#pragma unroll
    for (int off = 32; off >= 1; off >>= 1) part += __shfl_down(part, off, 64);
    __shared__ float ls[4];
    int wave = threadIdx.x >> 6;
    if ((threadIdx.x & 63) == 0) ls[wave] = part;
    __syncthreads();
    if (threadIdx.x == 0) atomicAdd(pooled, ls[0] + ls[1] + ls[2] + ls[3]);
}

__global__ void final_kernel(const float* __restrict__ pooled, const float* __restrict__ br,
                             float* __restrict__ out) {
    if (threadIdx.x == 0 && blockIdx.x == 0) out[0] = pooled[0] + br[0];
}

extern "C" void kernel_launch(void* const* d_in, const int* in_sizes, int n_in,
                              void* d_out, int out_size, void* d_ws, size_t ws_size,
                              hipStream_t stream) {
    const float* x    = (const float*)d_in[0];
    const int*   ei   = (const int*)d_in[1];
    const float* W1   = (const float*)d_in[2];
    const float* a_s1 = (const float*)d_in[3];
    const float* a_d1 = (const float*)d_in[4];
    const float* b1   = (const float*)d_in[5];
    const float* W2   = (const float*)d_in[6];
    const float* a_s2 = (const float*)d_in[7];
    const float* a_d2 = (const float*)d_in[8];
    const float* b2   = (const float*)d_in[9];
    const float* Wr   = (const float*)d_in[10];
    const float* br   = (const float*)d_in[11];
    float* out = (float*)d_out;

    int N = in_sizes[0] / FIN;
    int E = in_sizes[1] / 2;
    size_t n = (size_t)N;

    // workspace layout (floats); total = N*152 + 8 ≈ 60.8 MB
    float* ws  = (float*)d_ws;
    float* h1  = ws;             // N*64
    float* es1 = ws + n * 64;    // N*8
    float* ed1 = ws + n * 72;    // N*8
    float* d1  = ws + n * 80;    // N*8
    float* o1  = ws + n * 88;    // N*64
    float* pooled = ws + n * 152; // 1
    // reuse of dead regions for layer 2:
    float* h2  = h1;             // N*32 (h1 dead after edge1)
    float* o2  = h1 + n * 32;    // N*32
    float* es2 = es1;            // N   (es1/ed1 dead after edge1)
    float* ed2 = es1 + n;        // N
    float* d2  = es1 + 2 * n;    // N

    gemm1_kernel<<<N, 64, 0, stream>>>(x, W1, a_s1, a_d1, h1, es1, ed1, N);
    zero3_kernel<<<2048, 256, 0, stream>>>(o1, (long long)n * 64, d1, (long long)n * 8,
                                           nullptr, 0);
    long long t1 = (long long)(E + N) * F1;
    edge1_kernel<<<(int)((t1 + 255) / 256), 256, 0, stream>>>(ei, E, N, es1, ed1, h1, o1, d1);
    gemm2_kernel<<<(N + 1) / 2, 64, 0, stream>>>(o1, d1, b1, W2, a_s2, a_d2, h2, es2, ed2, N);
    zero3_kernel<<<2048, 256, 0, stream>>>(o2, (long long)n * 32, d2, (long long)n,
                                           pooled, 1);
    long long t2 = (long long)(E + N) * F2;
    edge2_kernel<<<(int)((t2 + 255) / 256), 256, 0, stream>>>(ei, E, N, es2, ed2, h2, o2, d2);
    reduce_kernel<<<1024, 256, 0, stream>>>(o2, d2, b2, Wr, pooled, N);
    final_kernel<<<1, 64, 0, stream>>>(pooled, br, out);
}

// Round 2
// 1063.375 us; speedup vs baseline: 1.5419x; 1.5419x over previous
//
#include <hip/hip_runtime.h>
#include <math.h>

#define NEG_SLOPE 0.2f
#define FIN 128
#define H1 8
#define F1 64   // HEADS1*HID
#define F2 32   // OUT2
#define SCAN_B 512

typedef unsigned short ushort_t;
typedef unsigned int uint_t;

static __device__ __forceinline__ ushort_t f2bf(float f) {
    uint_t u = __float_as_uint(f);
    u = (u + 0x7FFFu + ((u >> 16) & 1u)) >> 16; // RNE
    return (ushort_t)u;
}
static __device__ __forceinline__ float bf2f(ushort_t h) {
    return __uint_as_float(((uint_t)h) << 16);
}

// ---------------- Layer-1 GEMM: h1 = x @ W1 (bf16 out), fused e_src/e_dst ----
// 4 nodes per 256-thread block; one wave (64 lanes) per node, lane j = channel j
__global__ void gemm1_kernel(const float* __restrict__ x, const float* __restrict__ W1,
                             const float* __restrict__ a_src, const float* __restrict__ a_dst,
                             ushort_t* __restrict__ h1, float* __restrict__ es, float* __restrict__ ed,
                             int N) {
    int w = threadIdx.x >> 6;
    int j = threadIdx.x & 63;
    int n = blockIdx.x * 4 + w;
    __shared__ float xs[4][FIN];
    if (n < N) {
        xs[w][j]      = x[(size_t)n * FIN + j];
        xs[w][j + 64] = x[(size_t)n * FIN + 64 + j];
    }
    // wave-synchronous LDS use (written+read by same wave) — no barrier needed
    if (n >= N) return;
    float acc = 0.f;
#pragma unroll
    for (int k = 0; k < FIN; ++k) acc = fmaf(xs[w][k], W1[k * F1 + j], acc);
    h1[(size_t)n * F1 + j] = f2bf(acc);
    float vs = acc * a_src[j];
    float vd = acc * a_dst[j];
#pragma unroll
    for (int off = 4; off >= 1; off >>= 1) {
        vs += __shfl_down(vs, off, 8);
        vd += __shfl_down(vd, off, 8);
    }
    if ((j & 7) == 0) {
        es[n * H1 + (j >> 3)] = vs;
        ed[n * H1 + (j >> 3)] = vd;
    }
}

// ---------------- CSR build ------------------------------------------------
__global__ void zero_kernel(int* __restrict__ deg, int N, float* __restrict__ pooled) {
    int t = blockIdx.x * blockDim.x + threadIdx.x;
    int stride = gridDim.x * blockDim.x;
    for (int i = t; i < N; i += stride) deg[i] = 0;
    if (t == 0) pooled[0] = 0.f;
}

__global__ void hist_kernel(const int* __restrict__ ei, int E, int N, int* __restrict__ deg) {
    int t = blockIdx.x * blockDim.x + threadIdx.x;
    if (t >= E + N) return;
    int d = (t < E) ? ei[E + t] : (t - E);
    atomicAdd(&deg[d], 1);
}

// per-block sums of deg
__global__ void scanA_kernel(const int* __restrict__ deg, int N, int* __restrict__ bsum) {
    __shared__ int s[SCAN_B];
    int t = threadIdx.x;
    int i = blockIdx.x * SCAN_B + t;
    s[t] = (i < N) ? deg[i] : 0;
    __syncthreads();
    for (int o = SCAN_B / 2; o > 0; o >>= 1) {
        if (t < o) s[t] += s[t + o];
        __syncthreads();
    }
    if (t == 0) bsum[blockIdx.x] = s[0];
}

// exclusive scan of block sums (nblk <= SCAN_B)
__global__ void scanB_kernel(const int* __restrict__ bsum, int nblk, int* __restrict__ boff) {
    __shared__ int s[SCAN_B];
    int t = threadIdx.x;
    int v = (t < nblk) ? bsum[t] : 0;
    s[t] = v;
    __syncthreads();
    for (int o = 1; o < SCAN_B; o <<= 1) {
        int x = (t >= o) ? s[t - o] : 0;
        __syncthreads();
        s[t] += x;
        __syncthreads();
    }
    if (t < nblk) boff[t] = s[t] - v; // exclusive
}

// exclusive scan within block + block offset -> off (exclusive starts)
__global__ void scanC_kernel(const int* __restrict__ deg, int N, const int* __restrict__ boff,
                             int* __restrict__ off) {
    __shared__ int s[SCAN_B];
    int t = threadIdx.x;
    int i = blockIdx.x * SCAN_B + t;
    int v = (i < N) ? deg[i] : 0;
    s[t] = v;
    __syncthreads();
    for (int o = 1; o < SCAN_B; o <<= 1) {
        int x = (t >= o) ? s[t - o] : 0;
        __syncthreads();
        s[t] += x;
        __syncthreads();
    }
    if (i < N) off[i] = boff[blockIdx.x] + s[t] - v; // exclusive
}

// scatter src ids into dst-grouped buckets; off[d] advances from start(d) to end(d)
__global__ void scatter_kernel(const int* __restrict__ ei, int E, int N,
                               int* __restrict__ off, int* __restrict__ srcs) {
    int t = blockIdx.x * blockDim.x + threadIdx.x;
    if (t >= E + N) return;
    int s, d;
    if (t < E) { s = ei[t]; d = ei[E + t]; } else { s = d = t - E; }
    int pos = atomicAdd(&off[d], 1);
    srcs[pos] = s;
}
// post-scatter: off[d] == end(d); start(d) == (d ? off[d-1] : 0)

// ---------------- Layer-1 edge pass: gather per dst, normalized write --------
// one wave per dst node; lane j = channel j (head h = j>>3)
__global__ void edge1_gather(const int* __restrict__ off, const int* __restrict__ srcs,
                             const float* __restrict__ es, const float* __restrict__ ed,
                             const ushort_t* __restrict__ h1, float* __restrict__ o1, int N) {
    int d = (blockIdx.x * blockDim.x + threadIdx.x) >> 6;
    if (d >= N) return;
    int j = threadIdx.x & 63;
    int h = j >> 3;
    int start = (d == 0) ? 0 : off[d - 1];
    int end = off[d];
    float edv = ed[d * H1 + h];
    float acc = 0.f, wsum = 0.f;
    for (int k = start; k < end; ++k) {
        int s = srcs[k];
        float v = es[s * H1 + h] + edv;
        v = v > 0.f ? v : v * NEG_SLOPE;
        float w = __expf(v);
        acc = fmaf(w, bf2f(h1[(size_t)s * F1 + j]), acc);
        wsum += w;
    }
    o1[(size_t)d * F1 + j] = acc / wsum; // self-loop guarantees wsum > 0
}

// ---------------- Layer-2 GEMM: a1 = elu(o1 + b1); h2 = a1 @ W2 (bf16 out) ---
// 8 nodes per 256-thread block; 32 lanes per node
__global__ void gemm2_kernel(const float* __restrict__ o1, const float* __restrict__ b1,
                             const float* __restrict__ W2,
                             const float* __restrict__ a_src2, const float* __restrict__ a_dst2,
                             ushort_t* __restrict__ h2, float* __restrict__ es2,
                             float* __restrict__ ed2, int N) {
    int half = threadIdx.x >> 5;
    int n = blockIdx.x * 8 + half;
    int j = threadIdx.x & 31;
    __shared__ float a1s[8][F1];
    if (n < N) {
#pragma unroll
        for (int r = 0; r < 2; ++r) {
            int k = r * 32 + j;
            float v = o1[(size_t)n * F1 + k] + b1[k];
            a1s[half][k] = v > 0.f ? v : expm1f(v); // ELU
        }
    }
    __syncthreads();
    if (n >= N) return;
    float acc = 0.f;
#pragma unroll
    for (int k = 0; k < F1; ++k) acc = fmaf(a1s[half][k], W2[k * F2 + j], acc);
    h2[(size_t)n * F2 + j] = f2bf(acc);
    float vs = acc * a_src2[j];
    float vd = acc * a_dst2[j];
#pragma unroll
    for (int off = 16; off >= 1; off >>= 1) {
        vs += __shfl_down(vs, off, 32);
        vd += __shfl_down(vd, off, 32);
    }
    if (j == 0) { es2[n] = vs; ed2[n] = vd; }
}

// ---------------- Layer-2 edge pass: gather + fused global sum-pool dot Wr ---
// half-wave (32 lanes) per dst node; grid-stride; one atomic per block
__global__ void edge2_gather(const int* __restrict__ off, const int* __restrict__ srcs,
                             const float* __restrict__ es, const float* __restrict__ ed,
                             const ushort_t* __restrict__ h2,
                             const float* __restrict__ b2, const float* __restrict__ Wr,
                             float* __restrict__ pooled, int N) {
    int j = threadIdx.x & 31;
    int half_id = (blockIdx.x * blockDim.x + threadIdx.x) >> 5;
    int nhalves = (gridDim.x * blockDim.x) >> 5;
    float wr = Wr[j];
    float b2w = b2[j] * wr;
    float part = 0.f;
    for (int d = half_id; d < N; d += nhalves) {
        int start = (d == 0) ? 0 : off[d - 1];
        int end = off[d];
        float edv = ed[d];
        float acc = 0.f, wsum = 0.f;
        for (int k = start; k < end; ++k) {
            int s = srcs[k];
            float v = es[s] + edv;
            v = v > 0.f ? v : v * NEG_SLOPE;
            float w = __expf(v);
            acc = fmaf(w, bf2f(h2[(size_t)s * F2 + j]), acc);
            wsum += w;
        }
        part = fmaf(acc / wsum, wr, part + b2w);
    }
#pragma unroll
    for (int o = 32; o >= 1; o >>= 1) part += __shfl_down(part, o, 64);
    __shared__ float ls[4];
    int wave = threadIdx.x >> 6;
    if ((threadIdx.x & 63) == 0) ls[wave] = part;
    __syncthreads();
    if (threadIdx.x == 0) atomicAdd(pooled, ls[0] + ls[1] + ls[2] + ls[3]);
}

__global__ void final_kernel(const float* __restrict__ pooled, const float* __restrict__ br,
                             float* __restrict__ out) {
    if (threadIdx.x == 0 && blockIdx.x == 0) out[0] = pooled[0] + br[0];
}

extern "C" void kernel_launch(void* const* d_in, const int* in_sizes, int n_in,
                              void* d_out, int out_size, void* d_ws, size_t ws_size,
                              hipStream_t stream) {
    const float* x    = (const float*)d_in[0];
    const int*   ei   = (const int*)d_in[1];
    const float* W1   = (const float*)d_in[2];
    const float* a_s1 = (const float*)d_in[3];
    const float* a_d1 = (const float*)d_in[4];
    const float* b1   = (const float*)d_in[5];
    const float* W2   = (const float*)d_in[6];
    const float* a_s2 = (const float*)d_in[7];
    const float* a_d2 = (const float*)d_in[8];
    const float* b2   = (const float*)d_in[9];
    const float* Wr   = (const float*)d_in[10];
    const float* br   = (const float*)d_in[11];
    float* out = (float*)d_out;

    int N = in_sizes[0] / FIN;
    int E = in_sizes[1] / 2;
    size_t n = (size_t)N;

    // workspace layout (bytes), total ~= 58.8 MB for N=100k, E=3.2M
    char* ws = (char*)d_ws;
    float*    o1   = (float*)ws;                          // 64N f32
    float*    es1  = (float*)(ws + n * 256);              // 8N f32
    float*    ed1  = (float*)(ws + n * 288);              // 8N f32
    ushort_t* h1   = (ushort_t*)(ws + n * 320);           // 64N bf16
    int*      off  = (int*)(ws + n * 448);                // N int
    int*      deg  = (int*)(ws + n * 452);                // N int
    int*      srcs = (int*)(ws + n * 456);                // (E+N) int
    char*     tail = ws + n * 456 + (size_t)(E + N) * 4;
    int*      bsum = (int*)tail;                          // 512 int
    int*      boff = (int*)(tail + 2048);                 // 512 int
    float*  pooled = (float*)(tail + 4096);               // 1 f32
    // layer-2 overlays (regions dead after edge1):
    ushort_t* h2  = h1;      // 32N bf16
    float*    es2 = es1;     // N f32
    float*    ed2 = ed1;     // N f32

    int nblk = (N + SCAN_B - 1) / SCAN_B;
    int EN = E + N;

    zero_kernel<<<256, 256, 0, stream>>>(deg, N, pooled);
    gemm1_kernel<<<(N + 3) / 4, 256, 0, stream>>>(x, W1, a_s1, a_d1, h1, es1, ed1, N);
    hist_kernel<<<(EN + 255) / 256, 256, 0, stream>>>(ei, E, N, deg);
    scanA_kernel<<<nblk, SCAN_B, 0, stream>>>(deg, N, bsum);
    scanB_kernel<<<1, SCAN_B, 0, stream>>>(bsum, nblk, boff);
    scanC_kernel<<<nblk, SCAN_B, 0, stream>>>(deg, N, boff, off);
    scatter_kernel<<<(EN + 255) / 256, 256, 0, stream>>>(ei, E, N, off, srcs);
    edge1_gather<<<(N + 3) / 4, 256, 0, stream>>>(off, srcs, es1, ed1, h1, o1, N);
    gemm2_kernel<<<(N + 7) / 8, 256, 0, stream>>>(o1, b1, W2, a_s2, a_d2, h2, es2, ed2, N);
    edge2_gather<<<2048, 256, 0, stream>>>(off, srcs, es2, ed2, h2, b2, Wr, pooled, N);
    final_kernel<<<1, 64, 0, stream>>>(pooled, br, out);
}

// Round 3
// 886.304 us; speedup vs baseline: 1.8499x; 1.1998x over previous
//
#include <hip/hip_runtime.h>
#include <math.h>

#define NEG_SLOPE 0.2f
#define FIN 128
#define H1 8
#define F1 64   // HEADS1*HID
#define F2 32   // OUT2
#define SCAN_B 512

typedef unsigned short ushort_t;
typedef unsigned int uint_t;

static __device__ __forceinline__ ushort_t f2bf(float f) {
    uint_t u = __float_as_uint(f);
    u = (u + 0x7FFFu + ((u >> 16) & 1u)) >> 16; // RNE
    return (ushort_t)u;
}
static __device__ __forceinline__ float bf2f(ushort_t h) {
    return __uint_as_float(((uint_t)h) << 16);
}

// ---------------- Layer-1 GEMM: h1 = x @ W1 (bf16 out), fused e_src/e_dst ----
__global__ void gemm1_kernel(const float* __restrict__ x, const float* __restrict__ W1,
                             const float* __restrict__ a_src, const float* __restrict__ a_dst,
                             ushort_t* __restrict__ h1, float* __restrict__ es, float* __restrict__ ed,
                             int N) {
    int w = threadIdx.x >> 6;
    int j = threadIdx.x & 63;
    int n = blockIdx.x * 4 + w;
    __shared__ float xs[4][FIN];
    if (n < N) {
        xs[w][j]      = x[(size_t)n * FIN + j];
        xs[w][j + 64] = x[(size_t)n * FIN + 64 + j];
    }
    // wave-synchronous LDS (same wave writes & reads) — no barrier needed
    if (n >= N) return;
    float acc = 0.f;
#pragma unroll
    for (int k = 0; k < FIN; ++k) acc = fmaf(xs[w][k], W1[k * F1 + j], acc);
    h1[(size_t)n * F1 + j] = f2bf(acc);
    float vs = acc * a_src[j];
    float vd = acc * a_dst[j];
#pragma unroll
    for (int off = 4; off >= 1; off >>= 1) {
        vs += __shfl_down(vs, off, 8);
        vd += __shfl_down(vd, off, 8);
    }
    if ((j & 7) == 0) {
        es[n * H1 + (j >> 3)] = vs;
        ed[n * H1 + (j >> 3)] = vd;
    }
}

// ---------------- CSR build ------------------------------------------------
__global__ void zero_kernel(int* __restrict__ deg, int N, float* __restrict__ pooled) {
    int t = blockIdx.x * blockDim.x + threadIdx.x;
    int stride = gridDim.x * blockDim.x;
    for (int i = t; i < N; i += stride) deg[i] = 0;
    if (t == 0) pooled[0] = 0.f;
}

__global__ void hist_kernel(const int* __restrict__ ei, int E, int N, int* __restrict__ deg) {
    int t = blockIdx.x * blockDim.x + threadIdx.x;
    if (t >= E + N) return;
    int d = (t < E) ? ei[E + t] : (t - E);
    atomicAdd(&deg[d], 1);
}

__global__ void scanA_kernel(const int* __restrict__ deg, int N, int* __restrict__ bsum) {
    __shared__ int s[SCAN_B];
    int t = threadIdx.x;
    int i = blockIdx.x * SCAN_B + t;
    s[t] = (i < N) ? deg[i] : 0;
    __syncthreads();
    for (int o = SCAN_B / 2; o > 0; o >>= 1) {
        if (t < o) s[t] += s[t + o];
        __syncthreads();
    }
    if (t == 0) bsum[blockIdx.x] = s[0];
}

__global__ void scanB_kernel(const int* __restrict__ bsum, int nblk, int* __restrict__ boff) {
    __shared__ int s[SCAN_B];
    int t = threadIdx.x;
    int v = (t < nblk) ? bsum[t] : 0;
    s[t] = v;
    __syncthreads();
    for (int o = 1; o < SCAN_B; o <<= 1) {
        int x = (t >= o) ? s[t - o] : 0;
        __syncthreads();
        s[t] += x;
        __syncthreads();
    }
    if (t < nblk) boff[t] = s[t] - v; // exclusive
}

__global__ void scanC_kernel(const int* __restrict__ deg, int N, const int* __restrict__ boff,
                             int* __restrict__ off) {
    __shared__ int s[SCAN_B];
    int t = threadIdx.x;
    int i = blockIdx.x * SCAN_B + t;
    int v = (i < N) ? deg[i] : 0;
    s[t] = v;
    __syncthreads();
    for (int o = 1; o < SCAN_B; o <<= 1) {
        int x = (t >= o) ? s[t - o] : 0;
        __syncthreads();
        s[t] += x;
        __syncthreads();
    }
    if (i < N) off[i] = boff[blockIdx.x] + s[t] - v; // exclusive
}

__global__ void scatter_kernel(const int* __restrict__ ei, int E, int N,
                               int* __restrict__ off, int* __restrict__ srcs) {
    int t = blockIdx.x * blockDim.x + threadIdx.x;
    if (t >= E + N) return;
    int s, d;
    if (t < E) { s = ei[t]; d = ei[E + t]; } else { s = d = t - E; }
    int pos = atomicAdd(&off[d], 1);
    srcs[pos] = s;
}
// post-scatter: off[d] == end(d); start(d) == (d ? off[d-1] : 0)

// ---------------- Layer-1 edge pass: chunked gather, high MLP ----------------
// one wave per dst. Phase A: 8 edges x 8 heads of weights vectorized across
// 64 lanes. Phase B: 8 independent h1 row-gathers, fully unrolled.
__global__ void edge1_gather(const int* __restrict__ off, const int* __restrict__ srcs,
                             const float* __restrict__ es, const float* __restrict__ ed,
                             const ushort_t* __restrict__ h1, float* __restrict__ o1, int N) {
    int d = (blockIdx.x * blockDim.x + threadIdx.x) >> 6;
    if (d >= N) return;
    int j = threadIdx.x & 63;
    int e8 = j >> 3; // phase-A edge slot
    int h8 = j & 7;  // phase-A head
    int hB = j >> 3; // phase-B head (channel j belongs to head j>>3)
    int start = (d == 0) ? 0 : off[d - 1];
    int end = off[d];
    float edA = ed[d * H1 + h8];
    float acc = 0.f, wsumA = 0.f;
    for (int base = start; base < end; base += 8) {
        int cnt = end - base;
        if (cnt > 8) cnt = 8;
        int kk = base + e8;
        int s = srcs[kk < end ? kk : end - 1];
        float v = es[s * H1 + h8] + edA;
        v = v > 0.f ? v : v * NEG_SLOPE;
        float w = (e8 < cnt) ? __expf(v) : 0.f;
        wsumA += w;
        if (cnt == 8) {
#pragma unroll
            for (int k = 0; k < 8; ++k) {
                int ss = __shfl(s, k * 8, 64);
                float wk = __shfl(w, k * 8 + hB, 64);
                acc = fmaf(wk, bf2f(h1[(size_t)ss * F1 + j]), acc);
            }
        } else {
            for (int k = 0; k < cnt; ++k) {
                int ss = __shfl(s, k * 8, 64);
                float wk = __shfl(w, k * 8 + hB, 64);
                acc = fmaf(wk, bf2f(h1[(size_t)ss * F1 + j]), acc);
            }
        }
    }
    // sum w over the 8 edge-groups (lane bits 3..5): total weight per head (j&7)
    wsumA += __shfl_xor(wsumA, 8, 64);
    wsumA += __shfl_xor(wsumA, 16, 64);
    wsumA += __shfl_xor(wsumA, 32, 64);
    float wsum = __shfl(wsumA, hB, 64); // lane hB (<8) holds head hB's total
    o1[(size_t)d * F1 + j] = acc / wsum; // self-loop => wsum > 0
}

// ---------------- Layer-2 GEMM: a1 = elu(o1 + b1); h2 = a1 @ W2 (bf16) -------
__global__ void gemm2_kernel(const float* __restrict__ o1, const float* __restrict__ b1,
                             const float* __restrict__ W2,
                             const float* __restrict__ a_src2, const float* __restrict__ a_dst2,
                             ushort_t* __restrict__ h2, float* __restrict__ es2,
                             float* __restrict__ ed2, int N) {
    int half = threadIdx.x >> 5;
    int n = blockIdx.x * 8 + half;
    int j = threadIdx.x & 31;
    __shared__ float a1s[8][F1];
    if (n < N) {
#pragma unroll
        for (int r = 0; r < 2; ++r) {
            int k = r * 32 + j;
            float v = o1[(size_t)n * F1 + k] + b1[k];
            a1s[half][k] = v > 0.f ? v : expm1f(v); // ELU
        }
    }
    __syncthreads();
    if (n >= N) return;
    float acc = 0.f;
#pragma unroll
    for (int k = 0; k < F1; ++k) acc = fmaf(a1s[half][k], W2[k * F2 + j], acc);
    h2[(size_t)n * F2 + j] = f2bf(acc);
    float vs = acc * a_src2[j];
    float vd = acc * a_dst2[j];
#pragma unroll
    for (int off = 16; off >= 1; off >>= 1) {
        vs += __shfl_down(vs, off, 32);
        vd += __shfl_down(vd, off, 32);
    }
    if (j == 0) { es2[n] = vs; ed2[n] = vd; }
}

// ---------------- Layer-2 edge pass: chunked gather + fused pool·Wr ----------
// half-wave (32 lanes) per dst, grid-stride. Phase A: 32 edge weights
// vectorized per half. Phase B: unrolled h2 row-gathers with shfl broadcast.
__global__ void edge2_gather(const int* __restrict__ off, const int* __restrict__ srcs,
                             const float* __restrict__ es, const float* __restrict__ ed,
                             const ushort_t* __restrict__ h2,
                             const float* __restrict__ b2, const float* __restrict__ Wr,
                             float* __restrict__ pooled, int N) {
    int j = threadIdx.x & 31;          // channel
    int lanebase = threadIdx.x & 32;   // 0 or 32: this half's lane offset
    int half_id = (blockIdx.x * blockDim.x + threadIdx.x) >> 5;
    int nhalves = (gridDim.x * blockDim.x) >> 5;
    float wr = Wr[j];
    float b2w = b2[j] * wr;
    float part = 0.f;
    for (int d = half_id; d < N; d += nhalves) {
        int start = (d == 0) ? 0 : off[d - 1];
        int end = off[d];
        float edv = ed[d];
        float acc = 0.f, wsum = 0.f;
        for (int base = start; base < end; base += 32) {
            int cnt = end - base;
            if (cnt > 32) cnt = 32;
            int kk = base + j;
            int s = srcs[kk < end ? kk : end - 1];
            float v = es[s] + edv;
            v = v > 0.f ? v : v * NEG_SLOPE;
            float w = (j < cnt) ? __expf(v) : 0.f;
            wsum += w;
            if (cnt == 32) {
#pragma unroll
                for (int k = 0; k < 32; ++k) {
                    int ss = __shfl(s, lanebase + k, 64);
                    float wk = __shfl(w, lanebase + k, 64);
                    acc = fmaf(wk, bf2f(h2[(size_t)ss * F2 + j]), acc);
                }
            } else {
                for (int k = 0; k < cnt; ++k) {
                    int ss = __shfl(s, lanebase + k, 64);
                    float wk = __shfl(w, lanebase + k, 64);
                    acc = fmaf(wk, bf2f(h2[(size_t)ss * F2 + j]), acc);
                }
            }
        }
#pragma unroll
        for (int o = 16; o >= 1; o >>= 1) wsum += __shfl_xor(wsum, o, 32);
        part = fmaf(acc / wsum, wr, part + b2w);
    }
#pragma unroll
    for (int o = 32; o >= 1; o >>= 1) part += __shfl_down(part, o, 64);
    __shared__ float ls[4];
    int wave = threadIdx.x >> 6;
    if ((threadIdx.x & 63) == 0) ls[wave] = part;
    __syncthreads();
    if (threadIdx.x == 0) atomicAdd(pooled, ls[0] + ls[1] + ls[2] + ls[3]);
}

__global__ void final_kernel(const float* __restrict__ pooled, const float* __restrict__ br,
                             float* __restrict__ out) {
    if (threadIdx.x == 0 && blockIdx.x == 0) out[0] = pooled[0] + br[0];
}

extern "C" void kernel_launch(void* const* d_in, const int* in_sizes, int n_in,
                              void* d_out, int out_size, void* d_ws, size_t ws_size,
                              hipStream_t stream) {
    const float* x    = (const float*)d_in[0];
    const int*   ei   = (const int*)d_in[1];
    const float* W1   = (const float*)d_in[2];
    const float* a_s1 = (const float*)d_in[3];
    const float* a_d1 = (const float*)d_in[4];
    const float* b1   = (const float*)d_in[5];
    const float* W2   = (const float*)d_in[6];
    const float* a_s2 = (const float*)d_in[7];
    const float* a_d2 = (const float*)d_in[8];
    const float* b2   = (const float*)d_in[9];
    const float* Wr   = (const float*)d_in[10];
    const float* br   = (const float*)d_in[11];
    float* out = (float*)d_out;

    int N = in_sizes[0] / FIN;
    int E = in_sizes[1] / 2;
    size_t n = (size_t)N;

    // workspace layout (bytes), total ~= 58.8 MB for N=100k, E=3.2M
    char* ws = (char*)d_ws;
    float*    o1   = (float*)ws;                          // 64N f32
    float*    es1  = (float*)(ws + n * 256);              // 8N f32
    float*    ed1  = (float*)(ws + n * 288);              // 8N f32
    ushort_t* h1   = (ushort_t*)(ws + n * 320);           // 64N bf16
    int*      off  = (int*)(ws + n * 448);                // N int
    int*      deg  = (int*)(ws + n * 452);                // N int
    int*      srcs = (int*)(ws + n * 456);                // (E+N) int
    char*     tail = ws + n * 456 + (size_t)(E + N) * 4;
    int*      bsum = (int*)tail;                          // 512 int
    int*      boff = (int*)(tail + 2048);                 // 512 int
    float*  pooled = (float*)(tail + 4096);               // 1 f32
    // layer-2 overlays (regions dead after edge1):
    ushort_t* h2  = h1;      // 32N bf16
    float*    es2 = es1;     // N f32
    float*    ed2 = ed1;     // N f32

    int nblk = (N + SCAN_B - 1) / SCAN_B;
    int EN = E + N;

    zero_kernel<<<256, 256, 0, stream>>>(deg, N, pooled);
    gemm1_kernel<<<(N + 3) / 4, 256, 0, stream>>>(x, W1, a_s1, a_d1, h1, es1, ed1, N);
    hist_kernel<<<(EN + 255) / 256, 256, 0, stream>>>(ei, E, N, deg);
    scanA_kernel<<<nblk, SCAN_B, 0, stream>>>(deg, N, bsum);
    scanB_kernel<<<1, SCAN_B, 0, stream>>>(bsum, nblk, boff);
    scanC_kernel<<<nblk, SCAN_B, 0, stream>>>(deg, N, boff, off);
    scatter_kernel<<<(EN + 255) / 256, 256, 0, stream>>>(ei, E, N, off, srcs);
    edge1_gather<<<(N + 3) / 4, 256, 0, stream>>>(off, srcs, es1, ed1, h1, o1, N);
    gemm2_kernel<<<(N + 7) / 8, 256, 0, stream>>>(o1, b1, W2, a_s2, a_d2, h2, es2, ed2, N);
    edge2_gather<<<2048, 256, 0, stream>>>(off, srcs, es2, ed2, h2, b2, Wr, pooled, N);
    final_kernel<<<1, 64, 0, stream>>>(pooled, br, out);
}

// Round 4
// 547.164 us; speedup vs baseline: 2.9965x; 1.6198x over previous
//
#include <hip/hip_runtime.h>
#include <math.h>

#define NEG_SLOPE 0.2f
#define FIN 128
#define H1 8
#define F1 64   // HEADS1*HID
#define F2 32   // OUT2

#define SHIFT 6
#define BW 64          // dsts per bucket
#define CAP 4096       // max edges per bucket in LDS (avg ~2176, sigma ~66)
#define NBMAX 2048

typedef unsigned short ushort_t;
typedef unsigned int uint_t;

static __device__ __forceinline__ ushort_t f2bf(float f) {
    uint_t u = __float_as_uint(f);
    u = (u + 0x7FFFu + ((u >> 16) & 1u)) >> 16; // RNE
    return (ushort_t)u;
}
static __device__ __forceinline__ float bf2f(ushort_t h) {
    return __uint_as_float(((uint_t)h) << 16);
}

// ---------------- Layer-1 GEMM: h1 = x @ W1 (bf16 out), fused e_src/e_dst ----
__global__ void gemm1_kernel(const float* __restrict__ x, const float* __restrict__ W1,
                             const float* __restrict__ a_src, const float* __restrict__ a_dst,
                             ushort_t* __restrict__ h1, float* __restrict__ es, float* __restrict__ ed,
                             int N) {
    int w = threadIdx.x >> 6;
    int j = threadIdx.x & 63;
    int n = blockIdx.x * 4 + w;
    __shared__ float xs[4][FIN];
    if (n < N) {
        xs[w][j]      = x[(size_t)n * FIN + j];
        xs[w][j + 64] = x[(size_t)n * FIN + 64 + j];
    }
    // wave-synchronous LDS (same wave writes & reads)
    if (n >= N) return;
    float acc = 0.f;
#pragma unroll
    for (int k = 0; k < FIN; ++k) acc = fmaf(xs[w][k], W1[k * F1 + j], acc);
    h1[(size_t)n * F1 + j] = f2bf(acc);
    float vs = acc * a_src[j];
    float vd = acc * a_dst[j];
#pragma unroll
    for (int off = 4; off >= 1; off >>= 1) {
        vs += __shfl_down(vs, off, 8);
        vd += __shfl_down(vd, off, 8);
    }
    if ((j & 7) == 0) {
        es[n * H1 + (j >> 3)] = vs;
        ed[n * H1 + (j >> 3)] = vd;
    }
}

// ---------------- bucket CSR build ------------------------------------------
__global__ void zerob_kernel(int* __restrict__ bcnt, int NB, float* __restrict__ pooled) {
    int t = blockIdx.x * blockDim.x + threadIdx.x;
    int stride = gridDim.x * blockDim.x;
    for (int i = t; i < NB; i += stride) bcnt[i] = 0;
    if (t == 0) pooled[0] = 0.f;
}

// LDS-privatized bucket histogram over E+N items (self-loops appended)
__global__ void bhist_kernel(const int* __restrict__ ei, int E, int N,
                             int* __restrict__ bcnt, int NB) {
    __shared__ int h[NBMAX];
    int tid = threadIdx.x;
    for (int i = tid; i < NB; i += 256) h[i] = 0;
    __syncthreads();
    int EN = E + N;
    int chunk = (EN + gridDim.x - 1) / gridDim.x;
    int e0 = blockIdx.x * chunk;
    int e1 = e0 + chunk; if (e1 > EN) e1 = EN;
    for (int t = e0 + tid; t < e1; t += 256) {
        int d = (t < E) ? ei[E + t] : (t - E);
        atomicAdd(&h[d >> SHIFT], 1);
    }
    __syncthreads();
    for (int i = tid; i < NB; i += 256)
        if (h[i]) atomicAdd(&bcnt[i], h[i]);
}

// one-wave exclusive scan of bucket counts -> boff (+ cursor copy bcur)
__global__ void bscan_kernel(const int* __restrict__ bcnt, int NB,
                             int* __restrict__ boff, int* __restrict__ bcur) {
    int lane = threadIdx.x; // 0..63
    int chunk = (NB + 63) >> 6;
    int lo = lane * chunk;
    int hi = lo + chunk; if (hi > NB) hi = NB;
    int sum = 0;
    for (int i = lo; i < hi; ++i) sum += bcnt[i];
    int e = sum;
#pragma unroll
    for (int o = 1; o < 64; o <<= 1) {
        int v = __shfl_up(e, o, 64);
        if (lane >= o) e += v;
    }
    e -= sum; // exclusive prefix of this lane's chunk
    int run = e;
    for (int i = lo; i < hi; ++i) {
        int c = bcnt[i];
        boff[i] = run;
        bcur[i] = run;
        run += c;
    }
}

// block-aggregated bucket scatter: per-(block,bucket) runs -> long write runs
__global__ void bscat_kernel(const int* __restrict__ ei, int E, int N,
                             int* __restrict__ bcur, uint_t* __restrict__ pk, int NB) {
    __shared__ int lh[NBMAX]; // hist, then unused
    __shared__ int lc[NBMAX]; // global cursor per bucket for this block
    int tid = threadIdx.x;
    for (int i = tid; i < NB; i += 256) lh[i] = 0;
    __syncthreads();
    int EN = E + N;
    int chunk = (EN + gridDim.x - 1) / gridDim.x;
    int e0 = blockIdx.x * chunk;
    int e1 = e0 + chunk; if (e1 > EN) e1 = EN;
    for (int t = e0 + tid; t < e1; t += 256) {
        int d = (t < E) ? ei[E + t] : (t - E);
        atomicAdd(&lh[d >> SHIFT], 1);
    }
    __syncthreads();
    for (int i = tid; i < NB; i += 256) {
        int c = lh[i];
        lc[i] = c ? atomicAdd(&bcur[i], c) : 0;
    }
    __syncthreads();
    for (int t = e0 + tid; t < e1; t += 256) {
        int s, d;
        if (t < E) { s = ei[t]; d = ei[E + t]; } else { s = d = t - E; }
        int pos = atomicAdd(&lc[d >> SHIFT], 1);
        pk[pos] = ((uint_t)s << SHIFT) | (uint_t)(d & (BW - 1));
    }
}

// ---------------- Layer-1 edge pass: bucket-local CSR in LDS + gather --------
// one block per bucket (64 dsts); wave w handles 16 dsts; lane j = channel
__global__ void edge1_gather(const int* __restrict__ bcnt, const int* __restrict__ boff,
                             const uint_t* __restrict__ pk,
                             const float* __restrict__ es, const float* __restrict__ ed,
                             const ushort_t* __restrict__ h1, float* __restrict__ o1, int N) {
    int b = blockIdx.x;
    int d0 = b << SHIFT;
    int cnt = bcnt[b];
    int gbase = boff[b];
    int tid = threadIdx.x;
    int wv = tid >> 6;
    int j = tid & 63;
    int hB = j >> 3;
    __shared__ int ldeg[BW];
    __shared__ int loff[BW];
    __shared__ int lcur[BW];
    __shared__ int lsrc[CAP];
    if (cnt <= CAP) {
        if (tid < BW) ldeg[tid] = 0;
        __syncthreads();
        for (int k = tid; k < cnt; k += 256) atomicAdd(&ldeg[pk[gbase + k] & (BW - 1)], 1);
        __syncthreads();
        if (tid < 64) {
            int v = ldeg[tid];
            int e = v;
#pragma unroll
            for (int o = 1; o < 64; o <<= 1) {
                int u = __shfl_up(e, o, 64);
                if (tid >= o) e += u;
            }
            e -= v;
            loff[tid] = e;
            lcur[tid] = e;
        }
        __syncthreads();
        for (int k = tid; k < cnt; k += 256) {
            uint_t v = pk[gbase + k];
            int pos = atomicAdd(&lcur[v & (BW - 1)], 1);
            lsrc[pos] = (int)(v >> SHIFT);
        }
        __syncthreads();
        for (int ld = wv * 16; ld < wv * 16 + 16; ++ld) {
            int d = d0 + ld;
            if (d >= N) break;
            int st = loff[ld], dg = ldeg[ld];
            float edv = ed[d * H1 + hB];
            float acc = 0.f, wsum = 0.f;
#pragma unroll 4
            for (int k = st; k < st + dg; ++k) {
                int s = lsrc[k];
                float v = es[s * H1 + hB] + edv;
                v = v > 0.f ? v : v * NEG_SLOPE;
                float w = __expf(v);
                acc = fmaf(w, bf2f(h1[(size_t)s * F1 + j]), acc);
                wsum += w;
            }
            o1[(size_t)d * F1 + j] = acc / wsum; // self-loop => wsum > 0
        }
    } else {
        // slow fallback (statistically unreachable): scan whole bucket per dst
        for (int ld = wv * 16; ld < wv * 16 + 16; ++ld) {
            int d = d0 + ld;
            if (d >= N) break;
            float edv = ed[d * H1 + hB];
            float acc = 0.f, wsum = 0.f;
            for (int k = 0; k < cnt; ++k) {
                uint_t v = pk[gbase + k];
                if ((int)(v & (BW - 1)) != ld) continue;
                int s = (int)(v >> SHIFT);
                float e = es[s * H1 + hB] + edv;
                e = e > 0.f ? e : e * NEG_SLOPE;
                float w = __expf(e);
                acc = fmaf(w, bf2f(h1[(size_t)s * F1 + j]), acc);
                wsum += w;
            }
            o1[(size_t)d * F1 + j] = acc / wsum;
        }
    }
}

// ---------------- Layer-2 GEMM: a1 = elu(o1 + b1); h2 = a1 @ W2 (bf16) -------
__global__ void gemm2_kernel(const float* __restrict__ o1, const float* __restrict__ b1,
                             const float* __restrict__ W2,
                             const float* __restrict__ a_src2, const float* __restrict__ a_dst2,
                             ushort_t* __restrict__ h2, float* __restrict__ es2,
                             float* __restrict__ ed2, int N) {
    int half = threadIdx.x >> 5;
    int n = blockIdx.x * 8 + half;
    int j = threadIdx.x & 31;
    __shared__ float a1s[8][F1];
    if (n < N) {
#pragma unroll
        for (int r = 0; r < 2; ++r) {
            int k = r * 32 + j;
            float v = o1[(size_t)n * F1 + k] + b1[k];
            a1s[half][k] = v > 0.f ? v : expm1f(v); // ELU
        }
    }
    __syncthreads();
    if (n >= N) return;
    float acc = 0.f;
#pragma unroll
    for (int k = 0; k < F1; ++k) acc = fmaf(a1s[half][k], W2[k * F2 + j], acc);
    h2[(size_t)n * F2 + j] = f2bf(acc);
    float vs = acc * a_src2[j];
    float vd = acc * a_dst2[j];
#pragma unroll
    for (int off = 16; off >= 1; off >>= 1) {
        vs += __shfl_down(vs, off, 32);
        vd += __shfl_down(vd, off, 32);
    }
    if (j == 0) { es2[n] = vs; ed2[n] = vd; }
}

// ---------------- Layer-2 edge pass: LDS CSR + gather + fused pool·Wr --------
// one block per bucket; half-wave per dst (8 dsts per half-wave)
__global__ void edge2_gather(const int* __restrict__ bcnt, const int* __restrict__ boff,
                             const uint_t* __restrict__ pk,
                             const float* __restrict__ es, const float* __restrict__ ed,
                             const ushort_t* __restrict__ h2,
                             const float* __restrict__ b2, const float* __restrict__ Wr,
                             float* __restrict__ pooled, int N) {
    int b = blockIdx.x;
    int d0 = b << SHIFT;
    int cnt = bcnt[b];
    int gbase = boff[b];
    int tid = threadIdx.x;
    int hw = tid >> 5;  // 0..7
    int j = tid & 31;
    __shared__ int ldeg[BW];
    __shared__ int loff[BW];
    __shared__ int lcur[BW];
    __shared__ int lsrc[CAP];
    float wr = Wr[j];
    float b2w = b2[j] * wr;
    float part = 0.f;
    if (cnt <= CAP) {
        if (tid < BW) ldeg[tid] = 0;
        __syncthreads();
        for (int k = tid; k < cnt; k += 256) atomicAdd(&ldeg[pk[gbase + k] & (BW - 1)], 1);
        __syncthreads();
        if (tid < 64) {
            int v = ldeg[tid];
            int e = v;
#pragma unroll
            for (int o = 1; o < 64; o <<= 1) {
                int u = __shfl_up(e, o, 64);
                if (tid >= o) e += u;
            }
            e -= v;
            loff[tid] = e;
            lcur[tid] = e;
        }
        __syncthreads();
        for (int k = tid; k < cnt; k += 256) {
            uint_t v = pk[gbase + k];
            int pos = atomicAdd(&lcur[v & (BW - 1)], 1);
            lsrc[pos] = (int)(v >> SHIFT);
        }
        __syncthreads();
        for (int ld = hw * 8; ld < hw * 8 + 8; ++ld) {
            int d = d0 + ld;
            if (d >= N) break;
            int st = loff[ld], dg = ldeg[ld];
            float edv = ed[d];
            float acc = 0.f, wsum = 0.f;
#pragma unroll 4
            for (int k = st; k < st + dg; ++k) {
                int s = lsrc[k];
                float v = es[s] + edv;
                v = v > 0.f ? v : v * NEG_SLOPE;
                float w = __expf(v);
                acc = fmaf(w, bf2f(h2[(size_t)s * F2 + j]), acc);
                wsum += w;
            }
            part = fmaf(acc / wsum, wr, part + b2w);
        }
    } else {
        for (int ld = hw * 8; ld < hw * 8 + 8; ++ld) {
            int d = d0 + ld;
            if (d >= N) break;
            float edv = ed[d];
            float acc = 0.f, wsum = 0.f;
            for (int k = 0; k < cnt; ++k) {
                uint_t v = pk[gbase + k];
                if ((int)(v & (BW - 1)) != ld) continue;
                int s = (int)(v >> SHIFT);
                float e = es[s] + edv;
                e = e > 0.f ? e : e * NEG_SLOPE;
                float w = __expf(e);
                acc = fmaf(w, bf2f(h2[(size_t)s * F2 + j]), acc);
                wsum += w;
            }
            part = fmaf(acc / wsum, wr, part + b2w);
        }
    }
    // block reduction -> one atomic
#pragma unroll
    for (int o = 32; o >= 1; o >>= 1) part += __shfl_down(part, o, 64);
    __shared__ float ls[4];
    int wave = tid >> 6;
    if ((tid & 63) == 0) ls[wave] = part;
    __syncthreads();
    if (tid == 0) atomicAdd(pooled, ls[0] + ls[1] + ls[2] + ls[3]);
}

__global__ void final_kernel(const float* __restrict__ pooled, const float* __restrict__ br,
                             float* __restrict__ out) {
    if (threadIdx.x == 0 && blockIdx.x == 0) out[0] = pooled[0] + br[0];
}

extern "C" void kernel_launch(void* const* d_in, const int* in_sizes, int n_in,
                              void* d_out, int out_size, void* d_ws, size_t ws_size,
                              hipStream_t stream) {
    const float* x    = (const float*)d_in[0];
    const int*   ei   = (const int*)d_in[1];
    const float* W1   = (const float*)d_in[2];
    const float* a_s1 = (const float*)d_in[3];
    const float* a_d1 = (const float*)d_in[4];
    const float* b1   = (const float*)d_in[5];
    const float* W2   = (const float*)d_in[6];
    const float* a_s2 = (const float*)d_in[7];
    const float* a_d2 = (const float*)d_in[8];
    const float* b2   = (const float*)d_in[9];
    const float* Wr   = (const float*)d_in[10];
    const float* br   = (const float*)d_in[11];
    float* out = (float*)d_out;

    int N = in_sizes[0] / FIN;
    int E = in_sizes[1] / 2;
    size_t n = (size_t)N;
    int NB = (N + BW - 1) >> SHIFT;

    // workspace layout (bytes), total ~= 58 MB for N=100k, E=3.2M
    char* ws = (char*)d_ws;
    float*    o1   = (float*)ws;                          // 64N f32
    float*    es1  = (float*)(ws + n * 256);              // 8N f32
    float*    ed1  = (float*)(ws + n * 288);              // 8N f32
    ushort_t* h1   = (ushort_t*)(ws + n * 320);           // 64N bf16
    uint_t*   pk   = (uint_t*)(ws + n * 448);             // (E+N) uint
    char*     tail = ws + n * 448 + (size_t)(E + N) * 4;
    int*      bcnt = (int*)tail;                          // NBMAX int
    int*      boff = (int*)(tail + NBMAX * 4);            // NBMAX int
    int*      bcur = (int*)(tail + NBMAX * 8);            // NBMAX int
    float*  pooled = (float*)(tail + NBMAX * 12);         // 1 f32
    // layer-2 overlays (regions dead after edge1):
    ushort_t* h2  = h1;      // 32N bf16
    float*    es2 = es1;     // N f32
    float*    ed2 = ed1;     // N f32

    zerob_kernel<<<8, 256, 0, stream>>>(bcnt, NB, pooled);
    gemm1_kernel<<<(N + 3) / 4, 256, 0, stream>>>(x, W1, a_s1, a_d1, h1, es1, ed1, N);
    bhist_kernel<<<256, 256, 0, stream>>>(ei, E, N, bcnt, NB);
    bscan_kernel<<<1, 64, 0, stream>>>(bcnt, NB, boff, bcur);
    bscat_kernel<<<256, 256, 0, stream>>>(ei, E, N, bcur, pk, NB);
    edge1_gather<<<NB, 256, 0, stream>>>(bcnt, boff, pk, es1, ed1, h1, o1, N);
    gemm2_kernel<<<(N + 7) / 8, 256, 0, stream>>>(o1, b1, W2, a_s2, a_d2, h2, es2, ed2, N);
    edge2_gather<<<NB, 256, 0, stream>>>(bcnt, boff, pk, es2, ed2, h2, b2, Wr, pooled, N);
    final_kernel<<<1, 64, 0, stream>>>(pooled, br, out);
}